// Round 2
// baseline (1825.641 us; speedup 1.0000x reference)
//
#include <hip/hip_runtime.h>
#include <hip/hip_bf16.h>
#include <math.h>

#define NN 32768
#define LL 33
#define DD 128
#define EE 131072

// ---------------------------------------------------------------------------
// Mask layout detection: key_padding_mask is bool in the reference. The
// harness may hand it to us as int32 (4B/elem) or as raw bool bytes (1B/elem).
// For int32 0/1 values, every byte at position p%4!=0 is zero; for a byte
// mask, plenty of nonzero bytes land at p%4!=0 (lengths are random 1..33).
// Scanning the first NN*LL bytes is safe under both layouts.
// ---------------------------------------------------------------------------
__global__ __launch_bounds__(1024) void detect_mask_kernel(
    const unsigned char* __restrict__ mb, int* __restrict__ flag) {
  const int t = threadIdx.x;
  int found = 0;
  const int total = NN * LL;
  for (int p = t; p < total; p += 1024) {
    if ((p & 3) != 0 && mb[p] != 0) found = 1;
  }
  __shared__ int s;
  if (t == 0) s = 0;
  __syncthreads();
  if (found) atomicOr(&s, 1);
  __syncthreads();
  if (t == 0) *flag = s;  // 1 => byte mask, 0 => int32 mask
}

// lengths[i] = first j with mask[i][j] true (mask is monotone: j >= len)
__global__ __launch_bounds__(256) void lengths_kernel(
    const unsigned char* __restrict__ mb, const int* __restrict__ flag,
    int* __restrict__ lengths) {
  const int i = blockIdx.x * 256 + threadIdx.x;
  if (i >= NN) return;
  const int esz = (*flag) ? 1 : 4;
  int len = LL;
  for (int j = 1; j < LL; ++j) {
    if (mb[(size_t)(i * LL + j) * esz] != 0) { len = j; break; }
  }
  lengths[i] = len;
}

// ---------------------------------------------------------------------------
// Tiled fp32 GEMM: C[M,NO] = act(A[M,K] @ W[NO,K]^T + bias)
// BM=BN=128, K-chunks of 64 (zero-padded), k-major LDS tiles (stride 129),
// 8x8 per-thread micro-tile, 256 threads. M and NO must be multiples of 128.
// MODE 0: A is a plain row-major matrix.
// MODE 1: A row is the gathered node feature vector
//         [type_emb(64) | cat0(32) | cat1(32) | relu(deg*w+b)(32)], K=160.
// ---------------------------------------------------------------------------
template <int MODE>
__global__ __launch_bounds__(256) void gemm128(
    const float* __restrict__ A, const float* __restrict__ W,
    const float* __restrict__ bias, float* __restrict__ C,
    const int K, const int NO, const int relu,
    const int* __restrict__ ti, const int* __restrict__ ci,
    const float* __restrict__ ldg,
    const float* __restrict__ temb, const float* __restrict__ c0,
    const float* __restrict__ c1, const float* __restrict__ dw,
    const float* __restrict__ db) {
  __shared__ float As[64][129];
  __shared__ float Ws[64][129];
  const int t = threadIdx.x;
  const int bm = blockIdx.x * 128;
  const int bn = blockIdx.y * 128;
  const int kk = t & 63;   // lane-major k for coalesced global loads
  const int mb = t >> 6;
  const int m0 = (t >> 4) * 8;
  const int n0 = (t & 15) * 8;
  float acc[8][8];
#pragma unroll
  for (int i = 0; i < 8; ++i)
#pragma unroll
    for (int j = 0; j < 8; ++j) acc[i][j] = 0.f;

  const int nchunks = (K + 63) >> 6;
  for (int c = 0; c < nchunks; ++c) {
    const int gk = c * 64 + kk;
#pragma unroll
    for (int i = 0; i < 32; ++i) {
      const int m = mb + 4 * i;
      const int row = bm + m;
      float v = 0.f;
      if (MODE == 0) {
        if (gk < K) v = A[(size_t)row * K + gk];
      } else {
        if (gk < 64)       v = temb[(size_t)ti[row] * 64 + gk];
        else if (gk < 96)  v = c0[(size_t)ci[2 * row] * 32 + (gk - 64)];
        else if (gk < 128) v = c1[(size_t)ci[2 * row + 1] * 32 + (gk - 96)];
        else if (gk < 160) v = fmaxf(fmaf(ldg[row], dw[gk - 128], db[gk - 128]), 0.f);
      }
      As[kk][m] = v;
    }
#pragma unroll
    for (int i = 0; i < 32; ++i) {
      const int n = mb + 4 * i;
      Ws[kk][n] = (gk < K) ? W[(size_t)(bn + n) * K + gk] : 0.f;
    }
    __syncthreads();
#pragma unroll 2
    for (int k = 0; k < 64; ++k) {
      float a[8], b[8];
#pragma unroll
      for (int i = 0; i < 8; ++i) a[i] = As[k][m0 + i];
#pragma unroll
      for (int j = 0; j < 8; ++j) b[j] = Ws[k][n0 + j];
#pragma unroll
      for (int i = 0; i < 8; ++i)
#pragma unroll
        for (int j = 0; j < 8; ++j) acc[i][j] = fmaf(a[i], b[j], acc[i][j]);
    }
    __syncthreads();
  }
#pragma unroll
  for (int i = 0; i < 8; ++i) {
#pragma unroll
    for (int j = 0; j < 8; ++j) {
      float v = acc[i][j] + bias[bn + n0 + j];
      if (relu) v = fmaxf(v, 0.f);
      C[(size_t)(bm + m0 + i) * NO + (bn + n0 + j)] = v;
    }
  }
}

// ---------------------------------------------------------------------------
// Attention: one wave per node. QKV is [N,384] (Q|K|V col blocks).
// Lane covers dims {2*lane, 2*lane+1}; head = lane/16 (DH=32 -> 16 lanes).
// ---------------------------------------------------------------------------
__global__ __launch_bounds__(256) void attn_kernel(
    const float* __restrict__ QKV, const int* __restrict__ ctx,
    const int* __restrict__ lengths, float* __restrict__ O) {
  __shared__ int s_idx[4][33];
  __shared__ float s_p[4][4][33];
  const int t = threadIdx.x;
  const int w = t >> 6;
  const int lane = t & 63;
  const int node = blockIdx.x * 4 + w;
  const int len = lengths[node];
  if (lane < LL) s_idx[w][lane] = ctx[(size_t)node * LL + lane];
  const float2 q2 = *(const float2*)(QKV + (size_t)node * 384 + 2 * lane);
  __syncthreads();
  const int h = lane >> 4;
  // scores: per neighbor l, 16-lane group reduce gives one score per head
  for (int l = 0; l < len; ++l) {
    const int ki = s_idx[w][l];
    const float2 kv = *(const float2*)(QKV + (size_t)ki * 384 + 128 + 2 * lane);
    float part = q2.x * kv.x + q2.y * kv.y;
    part += __shfl_xor(part, 1);
    part += __shfl_xor(part, 2);
    part += __shfl_xor(part, 4);
    part += __shfl_xor(part, 8);
    if ((lane & 15) == 0) s_p[w][h][l] = part * 0.17677669529663687f; // 1/sqrt(32)
  }
  __syncthreads();
  // softmax per head over l < len (lane indexes l here)
#pragma unroll
  for (int hh = 0; hh < 4; ++hh) {
    float s = -INFINITY;
    if (lane < len) s = s_p[w][hh][lane];
    float m = s;
    m = fmaxf(m, __shfl_xor(m, 1));
    m = fmaxf(m, __shfl_xor(m, 2));
    m = fmaxf(m, __shfl_xor(m, 4));
    m = fmaxf(m, __shfl_xor(m, 8));
    m = fmaxf(m, __shfl_xor(m, 16));
    m = fmaxf(m, __shfl_xor(m, 32));
    float e = (lane < len) ? __expf(s - m) : 0.f;
    float sum = e;
    sum += __shfl_xor(sum, 1);
    sum += __shfl_xor(sum, 2);
    sum += __shfl_xor(sum, 4);
    sum += __shfl_xor(sum, 8);
    sum += __shfl_xor(sum, 16);
    sum += __shfl_xor(sum, 32);
    if (lane < LL) s_p[w][hh][lane] = e / sum;
  }
  __syncthreads();
  // attn @ V
  float2 o = make_float2(0.f, 0.f);
  for (int l = 0; l < len; ++l) {
    const float p = s_p[w][h][l];
    const int vi = s_idx[w][l];
    const float2 vv = *(const float2*)(QKV + (size_t)vi * 384 + 256 + 2 * lane);
    o.x = fmaf(p, vv.x, o.x);
    o.y = fmaf(p, vv.y, o.y);
  }
  *(float2*)(O + (size_t)node * DD + 2 * lane) = o;
}

// ---------------------------------------------------------------------------
// Fused edge MLP: per block, 32 edges.
// Phase 1: h1[32][128] = relu(concat(x[u],x[v],ef) @ W1^T + b1)  (K=258)
// Phase 2: wave-per-edge: lane j computes h2[j]=relu(W2[j]·h1+b2[j]);
//          logit = sum_j W3[j]*h2[j] + b3 via wave reduce.
// ---------------------------------------------------------------------------
__global__ __launch_bounds__(256) void edge_kernel(
    const float* __restrict__ x, const int* __restrict__ eu,
    const int* __restrict__ ev, const float* __restrict__ ef,
    const float* __restrict__ W1, const float* __restrict__ b1,
    const float* __restrict__ W2, const float* __restrict__ b2,
    const float* __restrict__ W3, const float* __restrict__ b3,
    float* __restrict__ out) {
  __shared__ float As[64][33];       // [k][edge]
  __shared__ float Ws[64 * 129];     // phase1: [k][n]; phase2: W2 [j][k]
  __shared__ float h1s[32][129];
  const int t = threadIdx.x;
  const int be = blockIdx.x * 32;
  const int kk = t & 63;
  const int mb = t >> 6;
  const int m0 = (t >> 5) * 4;  // 0..28
  const int n0 = (t & 31) * 4;  // 0..124
  float acc[4][4];
#pragma unroll
  for (int i = 0; i < 4; ++i)
#pragma unroll
    for (int j = 0; j < 4; ++j) acc[i][j] = 0.f;

  for (int c = 0; c < 5; ++c) {  // K=258 zero-padded to 320
    const int gk = c * 64 + kk;
#pragma unroll
    for (int i = 0; i < 8; ++i) {
      const int m = mb + 4 * i;
      const int e = be + m;
      float v = 0.f;
      if (gk < 128)      v = x[(size_t)eu[e] * DD + gk];
      else if (gk < 256) v = x[(size_t)ev[e] * DD + (gk - 128)];
      else if (gk < 258) v = ef[(size_t)e * 2 + (gk - 256)];
      As[kk][m] = v;
    }
#pragma unroll
    for (int i = 0; i < 32; ++i) {
      const int n = mb + 4 * i;
      Ws[kk * 129 + n] = (gk < 258) ? W1[(size_t)n * 258 + gk] : 0.f;
    }
    __syncthreads();
#pragma unroll 2
    for (int k = 0; k < 64; ++k) {
      float a[4], b[4];
#pragma unroll
      for (int i = 0; i < 4; ++i) a[i] = As[k][m0 + i];
#pragma unroll
      for (int j = 0; j < 4; ++j) b[j] = Ws[k * 129 + n0 + j];
#pragma unroll
      for (int i = 0; i < 4; ++i)
#pragma unroll
        for (int j = 0; j < 4; ++j) acc[i][j] = fmaf(a[i], b[j], acc[i][j]);
    }
    __syncthreads();
  }
#pragma unroll
  for (int i = 0; i < 4; ++i)
#pragma unroll
    for (int j = 0; j < 4; ++j)
      h1s[m0 + i][n0 + j] = fmaxf(acc[i][j] + b1[n0 + j], 0.f);
  __syncthreads();
  // restage W2 [64][128] into Ws (row-major, stride 129)
#pragma unroll
  for (int i = 0; i < 32; ++i) {
    const int idx = t + 256 * i;
    Ws[(idx >> 7) * 129 + (idx & 127)] = W2[idx];
  }
  __syncthreads();
  const int lane = t & 63;
  const int w = t >> 6;
  const float w3v = W3[lane];
  const float b2v = b2[lane];
  for (int el = w * 8; el < w * 8 + 8; ++el) {
    float acc2 = b2v;
#pragma unroll 4
    for (int k = 0; k < 128; ++k)
      acc2 = fmaf(Ws[lane * 129 + k], h1s[el][k], acc2);
    float val = fmaxf(acc2, 0.f) * w3v;
    val += __shfl_xor(val, 1);
    val += __shfl_xor(val, 2);
    val += __shfl_xor(val, 4);
    val += __shfl_xor(val, 8);
    val += __shfl_xor(val, 16);
    val += __shfl_xor(val, 32);
    if (lane == 0) out[be + el] = val + b3[0];
  }
}

// ---------------------------------------------------------------------------
extern "C" void kernel_launch(void* const* d_in, const int* in_sizes, int n_in,
                              void* d_out, int out_size, void* d_ws, size_t ws_size,
                              hipStream_t stream) {
  (void)in_sizes; (void)n_in; (void)out_size; (void)ws_size;
  const int*   type_idx   = (const int*)d_in[0];
  const int*   cat_idx    = (const int*)d_in[1];
  const float* log_degree = (const float*)d_in[2];
  const int*   ctx        = (const int*)d_in[3];
  const unsigned char* mask = (const unsigned char*)d_in[4];
  const int*   eu         = (const int*)d_in[5];
  const int*   ev         = (const int*)d_in[6];
  const float* ef         = (const float*)d_in[7];
  const float* type_embed = (const float*)d_in[8];
  const float* cat0       = (const float*)d_in[9];
  const float* cat1       = (const float*)d_in[10];
  const float* dw         = (const float*)d_in[11];
  const float* db         = (const float*)d_in[12];
  const float* proj_w     = (const float*)d_in[13];
  const float* proj_b     = (const float*)d_in[14];
  const float* qkv_w      = (const float*)d_in[15];
  const float* qkv_b      = (const float*)d_in[16];
  const float* out_w      = (const float*)d_in[17];
  const float* out_b      = (const float*)d_in[18];
  const float* w1         = (const float*)d_in[19];
  const float* b1         = (const float*)d_in[20];
  const float* w2         = (const float*)d_in[21];
  const float* b2         = (const float*)d_in[22];
  const float* w3         = (const float*)d_in[23];
  const float* b3         = (const float*)d_in[24];

  float* xbuf   = (float*)d_ws;                                // [N,128]
  float* qkvbuf = xbuf + (size_t)NN * DD;                      // [N,384]
  float* obuf   = qkvbuf + (size_t)NN * 384;                   // [N,128]
  int*   lengths = (int*)(obuf + (size_t)NN * DD);             // [N]
  int*   flag    = lengths + NN;                               // [1]

  detect_mask_kernel<<<1, 1024, 0, stream>>>(mask, flag);
  lengths_kernel<<<NN / 256, 256, 0, stream>>>(mask, flag, lengths);

  // encode: x = feat(160) @ proj_w^T + proj_b
  gemm128<1><<<dim3(NN / 128, 1), 256, 0, stream>>>(
      nullptr, proj_w, proj_b, xbuf, 160, 128, 0,
      type_idx, cat_idx, log_degree, type_embed, cat0, cat1, dw, db);

  for (int l = 0; l < 3; ++l) {
    gemm128<0><<<dim3(NN / 128, 3), 256, 0, stream>>>(
        xbuf, qkv_w + (size_t)l * 384 * DD, qkv_b + (size_t)l * 384, qkvbuf,
        DD, 384, 0, nullptr, nullptr, nullptr, nullptr, nullptr, nullptr,
        nullptr, nullptr);
    attn_kernel<<<NN / 4, 256, 0, stream>>>(qkvbuf, ctx, lengths, obuf);
    gemm128<0><<<dim3(NN / 128, 1), 256, 0, stream>>>(
        obuf, out_w + (size_t)l * DD * DD, out_b + (size_t)l * DD, xbuf,
        DD, 128, 1, nullptr, nullptr, nullptr, nullptr, nullptr, nullptr,
        nullptr, nullptr);
  }

  edge_kernel<<<EE / 32, 256, 0, stream>>>(
      xbuf, eu, ev, ef, w1, b1, w2, b2, w3, b3, (float*)d_out);
}

// Round 3
// 741.173 us; speedup vs baseline: 2.4632x; 2.4632x over previous
//
#include <hip/hip_runtime.h>
#include <hip/hip_bf16.h>
#include <math.h>

#define NN 32768
#define LL 33
#define DD 128
#define EE 131072

typedef short bf16x8 __attribute__((ext_vector_type(8)));
typedef float f32x4 __attribute__((ext_vector_type(4)));

__device__ inline unsigned short f2bf(float f) {
  __hip_bfloat16 h = __float2bfloat16(f);
  return *reinterpret_cast<unsigned short*>(&h);
}
__device__ inline float bf2f(unsigned short u) {
  return __uint_as_float(((unsigned int)u) << 16);
}
// async global->LDS, 16B per lane. LDS dest is wave-uniform base + lane*16;
// global src is per-lane (we pre-swizzle the SOURCE so LDS stays linear).
__device__ inline void gload16(const void* g, void* lds) {
  __builtin_amdgcn_global_load_lds(
      (const __attribute__((address_space(1))) unsigned int*)g,
      (__attribute__((address_space(3))) unsigned int*)lds, 16, 0, 0);
}

// ---------------------------------------------------------------------------
// mask layout detect + lengths (unchanged from fp32 baseline)
// ---------------------------------------------------------------------------
__global__ __launch_bounds__(1024) void detect_mask_kernel(
    const unsigned char* __restrict__ mb, int* __restrict__ flag) {
  const int t = threadIdx.x;
  int found = 0;
  const int total = NN * LL;
  for (int p = t; p < total; p += 1024) {
    if ((p & 3) != 0 && mb[p] != 0) found = 1;
  }
  __shared__ int s;
  if (t == 0) s = 0;
  __syncthreads();
  if (found) atomicOr(&s, 1);
  __syncthreads();
  if (t == 0) *flag = s;
}

__global__ __launch_bounds__(256) void lengths_kernel(
    const unsigned char* __restrict__ mb, const int* __restrict__ flag,
    int* __restrict__ lengths) {
  const int i = blockIdx.x * 256 + threadIdx.x;
  if (i >= NN) return;
  const int esz = (*flag) ? 1 : 4;
  int len = LL;
  for (int j = 1; j < LL; ++j) {
    if (mb[(size_t)(i * LL + j) * esz] != 0) { len = j; break; }
  }
  lengths[i] = len;
}

// ---------------------------------------------------------------------------
// prep: fp32 weights -> bf16 copies (with K-padding where needed)
// regions: qkvw[3*384*128] | outw[3*128*128] | projw->[128][192] pad |
//          w1 (x-part cols 0..255) -> [128][256] | w2[128][128]
// ---------------------------------------------------------------------------
__global__ __launch_bounds__(256) void prep_weights(
    const float* __restrict__ qkvw, const float* __restrict__ outw,
    const float* __restrict__ projw, const float* __restrict__ w1,
    const float* __restrict__ w2,
    unsigned short* __restrict__ qkvwbf, unsigned short* __restrict__ outwbf,
    unsigned short* __restrict__ projwbf, unsigned short* __restrict__ w1xbf,
    unsigned short* __restrict__ w2bf) {
  int i = blockIdx.x * 256 + threadIdx.x;
  const int n_qkv = 3 * 384 * 128, n_out = 3 * 128 * 128;
  const int n_proj = 128 * 192, n_w1 = 128 * 256, n_w2 = 128 * 128;
  if (i < n_qkv) { qkvwbf[i] = f2bf(qkvw[i]); return; }
  i -= n_qkv;
  if (i < n_out) { outwbf[i] = f2bf(outw[i]); return; }
  i -= n_out;
  if (i < n_proj) {
    int n = i / 192, c = i - n * 192;
    projwbf[i] = f2bf(c < 160 ? projw[n * 160 + c] : 0.f);
    return;
  }
  i -= n_proj;
  if (i < n_w1) {
    int n = i / 256, c = i - n * 256;
    w1xbf[i] = f2bf(w1[n * 258 + c]);
    return;
  }
  i -= n_w1;
  if (i < n_w2) w2bf[i] = f2bf(w2[i]);
}

// ---------------------------------------------------------------------------
// feat_build: bf16 feature matrix [NN][192]
// [type_emb(64) | cat0(32) | cat1(32) | relu(deg)(32) | zeros(32)]
// ---------------------------------------------------------------------------
__global__ __launch_bounds__(256) void feat_build(
    const int* __restrict__ ti, const int* __restrict__ ci,
    const float* __restrict__ ldg, const float* __restrict__ temb,
    const float* __restrict__ c0, const float* __restrict__ c1,
    const float* __restrict__ dw, const float* __restrict__ db,
    unsigned short* __restrict__ feat) {
  const int i = blockIdx.x * 256 + threadIdx.x;
  if (i >= NN * 192) return;
  const int n = i / 192, c = i - n * 192;
  float v;
  if (c < 64)       v = temb[(size_t)ti[n] * 64 + c];
  else if (c < 96)  v = c0[(size_t)ci[2 * n] * 32 + (c - 64)];
  else if (c < 128) v = c1[(size_t)ci[2 * n + 1] * 32 + (c - 96)];
  else if (c < 160) v = fmaxf(fmaf(ldg[n], dw[c - 128], db[c - 128]), 0.f);
  else              v = 0.f;
  feat[i] = f2bf(v);
}

// ---------------------------------------------------------------------------
// bf16 MFMA GEMM: C[M,NO] = act(A @ W^T + bias), 128x128 tile, BK=64.
// A: bf16 rows of a_rs bytes; W: bf16 [NO][K] rows of w_rs bytes.
// 4 waves in 2x2; per wave 64x64 via 4x4 frags of 16x16x32.
// LDS tiles [128 rows][128 B] with XOR-swizzle byte^((row&7)<<4), applied on
// the global SOURCE address (T2/m173) so global_load_lds dest stays linear.
// ---------------------------------------------------------------------------
__global__ __launch_bounds__(256) void mfma_gemm(
    const char* __restrict__ A, int a_rs, const char* __restrict__ W, int w_rs,
    const float* __restrict__ bias, int nsteps, int relu,
    unsigned short* __restrict__ C, int c_rs) {
  __shared__ char As[16384];
  __shared__ char Bs[16384];
  const int t = threadIdx.x, l = t & 63, w = t >> 6;
  const int bm = blockIdx.x * 128, bn = blockIdx.y * 128;
  const int wr = w >> 1, wc = w & 1;
  f32x4 acc[4][4];
#pragma unroll
  for (int mi = 0; mi < 4; ++mi)
#pragma unroll
    for (int ni = 0; ni < 4; ++ni)
#pragma unroll
      for (int j = 0; j < 4; ++j) acc[mi][ni][j] = 0.f;

  for (int ks = 0; ks < nsteps; ++ks) {
#pragma unroll
    for (int i = 0; i < 4; ++i) {
      const int row = w * 32 + i * 8 + (l >> 3);
      const int ch = (l & 7) ^ (row & 7);
      gload16(A + (size_t)(bm + row) * a_rs + ks * 128 + ch * 16,
              As + w * 4096 + i * 1024);
      gload16(W + (size_t)(bn + row) * w_rs + ks * 128 + ch * 16,
              Bs + w * 4096 + i * 1024);
    }
    __syncthreads();
#pragma unroll
    for (int k0 = 0; k0 < 2; ++k0) {
      bf16x8 af[4], bff[4];
#pragma unroll
      for (int mi = 0; mi < 4; ++mi) {
        const int r = wr * 64 + mi * 16 + (l & 15);
        const int off = (k0 * 64 + (l >> 4) * 16) ^ ((r & 7) << 4);
        af[mi] = *(const bf16x8*)(As + r * 128 + off);
      }
#pragma unroll
      for (int ni = 0; ni < 4; ++ni) {
        const int r = wc * 64 + ni * 16 + (l & 15);
        const int off = (k0 * 64 + (l >> 4) * 16) ^ ((r & 7) << 4);
        bff[ni] = *(const bf16x8*)(Bs + r * 128 + off);
      }
#pragma unroll
      for (int mi = 0; mi < 4; ++mi)
#pragma unroll
        for (int ni = 0; ni < 4; ++ni)
          acc[mi][ni] = __builtin_amdgcn_mfma_f32_16x16x32_bf16(
              af[mi], bff[ni], acc[mi][ni], 0, 0, 0);
    }
    __syncthreads();
  }
  // epilogue: C/D layout col=lane&15, row=(lane>>4)*4+j
#pragma unroll
  for (int ni = 0; ni < 4; ++ni) {
    const int col = bn + wc * 64 + ni * 16 + (l & 15);
    const float bz = bias[col];
#pragma unroll
    for (int mi = 0; mi < 4; ++mi)
#pragma unroll
      for (int j = 0; j < 4; ++j) {
        const int row = bm + wr * 64 + mi * 16 + (l >> 4) * 4 + j;
        float v = acc[mi][ni][j] + bz;
        if (relu) v = fmaxf(v, 0.f);
        C[(size_t)row * c_rs + col] = f2bf(v);
      }
  }
}

// ---------------------------------------------------------------------------
// Attention on bf16 QKV [N][384]: wave per node, fp32 math.
// ---------------------------------------------------------------------------
__global__ __launch_bounds__(256) void attn_kernel(
    const unsigned short* __restrict__ QKV, const int* __restrict__ ctx,
    const int* __restrict__ lengths, unsigned short* __restrict__ O) {
  __shared__ int s_idx[4][33];
  __shared__ float s_p[4][4][33];
  const int t = threadIdx.x;
  const int w = t >> 6;
  const int lane = t & 63;
  const int node = blockIdx.x * 4 + w;
  const int len = lengths[node];
  if (lane < LL) s_idx[w][lane] = ctx[(size_t)node * LL + lane];
  const unsigned int qu = *(const unsigned int*)(QKV + (size_t)node * 384 + 2 * lane);
  const float qx = bf2f((unsigned short)qu), qy = bf2f((unsigned short)(qu >> 16));
  __syncthreads();
  const int h = lane >> 4;
  for (int l = 0; l < len; ++l) {
    const int ki = s_idx[w][l];
    const unsigned int ku = *(const unsigned int*)(QKV + (size_t)ki * 384 + 128 + 2 * lane);
    float part = qx * bf2f((unsigned short)ku) + qy * bf2f((unsigned short)(ku >> 16));
    part += __shfl_xor(part, 1);
    part += __shfl_xor(part, 2);
    part += __shfl_xor(part, 4);
    part += __shfl_xor(part, 8);
    if ((lane & 15) == 0) s_p[w][h][l] = part * 0.17677669529663687f;
  }
  __syncthreads();
#pragma unroll
  for (int hh = 0; hh < 4; ++hh) {
    float s = -INFINITY;
    if (lane < len) s = s_p[w][hh][lane];
    float m = s;
    m = fmaxf(m, __shfl_xor(m, 1));
    m = fmaxf(m, __shfl_xor(m, 2));
    m = fmaxf(m, __shfl_xor(m, 4));
    m = fmaxf(m, __shfl_xor(m, 8));
    m = fmaxf(m, __shfl_xor(m, 16));
    m = fmaxf(m, __shfl_xor(m, 32));
    float e = (lane < len) ? __expf(s - m) : 0.f;
    float sum = e;
    sum += __shfl_xor(sum, 1);
    sum += __shfl_xor(sum, 2);
    sum += __shfl_xor(sum, 4);
    sum += __shfl_xor(sum, 8);
    sum += __shfl_xor(sum, 16);
    sum += __shfl_xor(sum, 32);
    if (lane < LL) s_p[w][hh][lane] = e / sum;
  }
  __syncthreads();
  float ox = 0.f, oy = 0.f;
  for (int l = 0; l < len; ++l) {
    const float p = s_p[w][h][l];
    const int vi = s_idx[w][l];
    const unsigned int vu = *(const unsigned int*)(QKV + (size_t)vi * 384 + 256 + 2 * lane);
    ox = fmaf(p, bf2f((unsigned short)vu), ox);
    oy = fmaf(p, bf2f((unsigned short)(vu >> 16)), oy);
  }
  const unsigned int ou = ((unsigned int)f2bf(oy) << 16) | f2bf(ox);
  *(unsigned int*)(O + (size_t)node * DD + 2 * lane) = ou;
}

// ---------------------------------------------------------------------------
// Fused edge MLP, 128 edges/block, all-MFMA:
// phase1: h1 = relu([x_u|x_v] @ W1x^T + ef-fixup(fp32) + b1) -> bf16 LDS (swz)
// phase2: h2acc = h1 @ W2^T (MFMA)
// phase3: logit = sum relu(h2+b2)*w3 + b3 (fp32, deterministic LDS partials)
// ---------------------------------------------------------------------------
__global__ __launch_bounds__(256) void edge_fused(
    const char* __restrict__ xbf, const int* __restrict__ eu,
    const int* __restrict__ ev, const float* __restrict__ ef,
    const char* __restrict__ w1x, const float* __restrict__ w1f,
    const float* __restrict__ b1, const char* __restrict__ w2,
    const float* __restrict__ b2, const float* __restrict__ w3,
    const float* __restrict__ b3, float* __restrict__ out) {
  __shared__ char lds[65536];
  char* As = lds;                // 16 KB (phase1 A; phase3 partials overlay)
  char* Bs = lds + 16384;        // 16 KB (W1x slice, then W2 slices)
  char* H1 = lds + 32768;        // 32 KB bf16 [128][256B] swizzled
  float* s_part = (float*)lds;   // [2][128], used after As is dead
  const int t = threadIdx.x, l = t & 63, w = t >> 6;
  const int bm = blockIdx.x * 128;
  const int wr = w >> 1, wc = w & 1;
  f32x4 acc[4][4];
#pragma unroll
  for (int mi = 0; mi < 4; ++mi)
#pragma unroll
    for (int ni = 0; ni < 4; ++ni)
#pragma unroll
      for (int j = 0; j < 4; ++j) acc[mi][ni][j] = 0.f;

  for (int ks = 0; ks < 4; ++ks) {
    const int* idxp = (ks < 2) ? eu : ev;
#pragma unroll
    for (int i = 0; i < 4; ++i) {
      const int row = w * 32 + i * 8 + (l >> 3);
      const int ch = (l & 7) ^ (row & 7);
      const int nidx = idxp[bm + row];
      gload16(xbf + (size_t)nidx * 256 + (ks & 1) * 128 + ch * 16,
              As + w * 4096 + i * 1024);
      gload16(w1x + (size_t)row * 512 + ks * 128 + ch * 16,
              Bs + w * 4096 + i * 1024);
    }
    __syncthreads();
#pragma unroll
    for (int k0 = 0; k0 < 2; ++k0) {
      bf16x8 af[4], bff[4];
#pragma unroll
      for (int mi = 0; mi < 4; ++mi) {
        const int r = wr * 64 + mi * 16 + (l & 15);
        const int off = (k0 * 64 + (l >> 4) * 16) ^ ((r & 7) << 4);
        af[mi] = *(const bf16x8*)(As + r * 128 + off);
      }
#pragma unroll
      for (int ni = 0; ni < 4; ++ni) {
        const int r = wc * 64 + ni * 16 + (l & 15);
        const int off = (k0 * 64 + (l >> 4) * 16) ^ ((r & 7) << 4);
        bff[ni] = *(const bf16x8*)(Bs + r * 128 + off);
      }
#pragma unroll
      for (int mi = 0; mi < 4; ++mi)
#pragma unroll
        for (int ni = 0; ni < 4; ++ni)
          acc[mi][ni] = __builtin_amdgcn_mfma_f32_16x16x32_bf16(
              af[mi], bff[ni], acc[mi][ni], 0, 0, 0);
    }
    __syncthreads();
  }
  // fp32 ef fixup (k=256,257) + bias + relu -> H1 bf16 (swizzled)
  float w1c0[4], w1c1[4], bb[4];
#pragma unroll
  for (int ni = 0; ni < 4; ++ni) {
    const int col = wc * 64 + ni * 16 + (l & 15);
    w1c0[ni] = w1f[col * 258 + 256];
    w1c1[ni] = w1f[col * 258 + 257];
    bb[ni] = b1[col];
  }
#pragma unroll
  for (int mi = 0; mi < 4; ++mi)
#pragma unroll
    for (int j = 0; j < 4; ++j) {
      const int rl = wr * 64 + mi * 16 + (l >> 4) * 4 + j;
      const float2 e2 = *(const float2*)(ef + 2 * (size_t)(bm + rl));
#pragma unroll
      for (int ni = 0; ni < 4; ++ni) {
        float v = acc[mi][ni][j] + e2.x * w1c0[ni] + e2.y * w1c1[ni] + bb[ni];
        v = fmaxf(v, 0.f);
        const int col = wc * 64 + ni * 16 + (l & 15);
        const int off = (col * 2) ^ ((rl & 7) << 4);
        *(unsigned short*)(H1 + rl * 256 + off) = f2bf(v);
      }
    }
  __syncthreads();
  f32x4 acc2[4][4];
#pragma unroll
  for (int mi = 0; mi < 4; ++mi)
#pragma unroll
    for (int ni = 0; ni < 4; ++ni)
#pragma unroll
      for (int j = 0; j < 4; ++j) acc2[mi][ni][j] = 0.f;
  for (int ks2 = 0; ks2 < 2; ++ks2) {
#pragma unroll
    for (int i = 0; i < 4; ++i) {
      const int row = w * 32 + i * 8 + (l >> 3);
      const int ch = (l & 7) ^ (row & 7);
      gload16(w2 + (size_t)row * 256 + ks2 * 128 + ch * 16,
              Bs + w * 4096 + i * 1024);
    }
    __syncthreads();
#pragma unroll
    for (int k0 = 0; k0 < 2; ++k0) {
      bf16x8 af[4], bff[4];
#pragma unroll
      for (int mi = 0; mi < 4; ++mi) {
        const int r = wr * 64 + mi * 16 + (l & 15);
        const int off = (ks2 * 128 + k0 * 64 + (l >> 4) * 16) ^ ((r & 7) << 4);
        af[mi] = *(const bf16x8*)(H1 + r * 256 + off);
      }
#pragma unroll
      for (int ni = 0; ni < 4; ++ni) {
        const int r = wc * 64 + ni * 16 + (l & 15);
        const int off = (k0 * 64 + (l >> 4) * 16) ^ ((r & 7) << 4);
        bff[ni] = *(const bf16x8*)(Bs + r * 128 + off);
      }
#pragma unroll
      for (int mi = 0; mi < 4; ++mi)
#pragma unroll
        for (int ni = 0; ni < 4; ++ni)
          acc2[mi][ni] = __builtin_amdgcn_mfma_f32_16x16x32_bf16(
              af[mi], bff[ni], acc2[mi][ni], 0, 0, 0);
    }
    __syncthreads();
  }
  // phase 3: relu(h2+b2)*w3, fp32, deterministic partials
  float b2v[4], w3v[4];
#pragma unroll
  for (int ni = 0; ni < 4; ++ni) {
    const int col = wc * 64 + ni * 16 + (l & 15);
    b2v[ni] = b2[col];
    w3v[ni] = w3[col];
  }
#pragma unroll
  for (int mi = 0; mi < 4; ++mi)
#pragma unroll
    for (int j = 0; j < 4; ++j) {
      const int rl = wr * 64 + mi * 16 + (l >> 4) * 4 + j;
      float p = 0.f;
#pragma unroll
      for (int ni = 0; ni < 4; ++ni) {
        const float h2 = fmaxf(acc2[mi][ni][j] + b2v[ni], 0.f);
        p = fmaf(h2, w3v[ni], p);
      }
      p += __shfl_xor(p, 1);
      p += __shfl_xor(p, 2);
      p += __shfl_xor(p, 4);
      p += __shfl_xor(p, 8);
      if ((l & 15) == 0) s_part[wc * 128 + rl] = p;
    }
  __syncthreads();
  if (t < 128) out[bm + t] = s_part[t] + s_part[128 + t] + b3[0];
}

// ---------------------------------------------------------------------------
extern "C" void kernel_launch(void* const* d_in, const int* in_sizes, int n_in,
                              void* d_out, int out_size, void* d_ws, size_t ws_size,
                              hipStream_t stream) {
  (void)in_sizes; (void)n_in; (void)out_size; (void)ws_size;
  const int*   type_idx   = (const int*)d_in[0];
  const int*   cat_idx    = (const int*)d_in[1];
  const float* log_degree = (const float*)d_in[2];
  const int*   ctx        = (const int*)d_in[3];
  const unsigned char* mask = (const unsigned char*)d_in[4];
  const int*   eu         = (const int*)d_in[5];
  const int*   ev         = (const int*)d_in[6];
  const float* ef         = (const float*)d_in[7];
  const float* type_embed = (const float*)d_in[8];
  const float* cat0       = (const float*)d_in[9];
  const float* cat1       = (const float*)d_in[10];
  const float* dw         = (const float*)d_in[11];
  const float* db         = (const float*)d_in[12];
  const float* proj_w     = (const float*)d_in[13];
  const float* proj_b     = (const float*)d_in[14];
  const float* qkv_w      = (const float*)d_in[15];
  const float* qkv_b      = (const float*)d_in[16];
  const float* out_w      = (const float*)d_in[17];
  const float* out_b      = (const float*)d_in[18];
  const float* w1         = (const float*)d_in[19];
  const float* b1         = (const float*)d_in[20];
  const float* w2         = (const float*)d_in[21];
  const float* b2         = (const float*)d_in[22];
  const float* w3         = (const float*)d_in[23];
  const float* b3         = (const float*)d_in[24];

  char* ws = (char*)d_ws;
  char* xbf     = ws;                       // [N][128] bf16   8 MB
  char* qkvbf   = ws + 8388608;             // [N][384] bf16   24 MB
  char* obf     = ws + 33554432;            // [N][128] bf16   8 MB
  char* featbf  = ws + 41943040;            // [N][192] bf16   12 MB
  char* qkvwbf  = ws + 54525952;            // 3*384*128 bf16
  char* outwbf  = ws + 54820864;            // 3*128*128 bf16
  char* projwbf = ws + 54919168;            // 128*192 bf16
  char* w1xbf   = ws + 54968320;            // 128*256 bf16
  char* w2bf    = ws + 55033856;            // 128*128 bf16
  int*  lengths = (int*)(ws + 55066624);
  int*  flag    = (int*)(ws + 55197696);

  prep_weights<<<1056, 256, 0, stream>>>(
      qkv_w, out_w, proj_w, w1, w2,
      (unsigned short*)qkvwbf, (unsigned short*)outwbf,
      (unsigned short*)projwbf, (unsigned short*)w1xbf, (unsigned short*)w2bf);
  feat_build<<<NN * 192 / 256, 256, 0, stream>>>(
      type_idx, cat_idx, log_degree, type_embed, cat0, cat1, dw, db,
      (unsigned short*)featbf);
  detect_mask_kernel<<<1, 1024, 0, stream>>>(mask, flag);
  lengths_kernel<<<NN / 256, 256, 0, stream>>>(mask, flag, lengths);

  // encode: x = feat[192] @ projw^T + proj_b (no relu)
  mfma_gemm<<<dim3(NN / 128, 1), 256, 0, stream>>>(
      featbf, 384, projwbf, 384, proj_b, 3, 0, (unsigned short*)xbf, 128);

  for (int layer = 0; layer < 3; ++layer) {
    mfma_gemm<<<dim3(NN / 128, 3), 256, 0, stream>>>(
        xbf, 256, qkvwbf + (size_t)layer * 98304, 256,
        qkv_b + (size_t)layer * 384, 2, 0, (unsigned short*)qkvbf, 384);
    attn_kernel<<<NN / 4, 256, 0, stream>>>(
        (const unsigned short*)qkvbf, ctx, lengths, (unsigned short*)obf);
    mfma_gemm<<<dim3(NN / 128, 1), 256, 0, stream>>>(
        obf, 256, outwbf + (size_t)layer * 32768, 256,
        out_b + (size_t)layer * 128, 2, 1, (unsigned short*)xbf, 128);
  }

  edge_fused<<<EE / 128, 256, 0, stream>>>(
      xbf, eu, ev, ef, w1xbf, w1, b1, w2bf, b2, w3, b3, (float*)d_out);
}

// Round 4
// 400.844 us; speedup vs baseline: 4.5545x; 1.8490x over previous
//
#include <hip/hip_runtime.h>
#include <hip/hip_bf16.h>
#include <math.h>

#define NN 32768
#define LL 33
#define DD 128
#define EE 131072

typedef short bf16x8 __attribute__((ext_vector_type(8)));
typedef float f32x4 __attribute__((ext_vector_type(4)));

__device__ inline unsigned short f2bf(float f) {
  __hip_bfloat16 h = __float2bfloat16(f);
  return *reinterpret_cast<unsigned short*>(&h);
}
__device__ inline float bf2f(unsigned short u) {
  return __uint_as_float(((unsigned int)u) << 16);
}
// async global->LDS, 16B per lane. LDS dest is wave-uniform base + lane*16;
// global src is per-lane (we pre-swizzle the SOURCE so LDS stays linear).
__device__ inline void gload16(const void* g, void* lds) {
  __builtin_amdgcn_global_load_lds(
      (const __attribute__((address_space(1))) unsigned int*)g,
      (__attribute__((address_space(3))) unsigned int*)lds, 16, 0, 0);
}

// ---------------------------------------------------------------------------
// Parallel mask-layout detect. Reads the first NN*LL bytes (safe under both
// layouts) as dwords; a nonzero byte at p%4!=0 <=> (dword & 0xFFFFFF00) != 0
// <=> byte-layout mask. flag must be zeroed beforehand (hipMemsetAsync).
// ---------------------------------------------------------------------------
__global__ __launch_bounds__(256) void detect_mask_kernel(
    const unsigned int* __restrict__ mw, int* __restrict__ flag) {
  const int nd = NN * LL / 4;
  int found = 0;
  for (int p = blockIdx.x * 256 + threadIdx.x; p < nd; p += gridDim.x * 256) {
    if (mw[p] & 0xFFFFFF00u) found = 1;
  }
  __shared__ int s;
  if (threadIdx.x == 0) s = 0;
  __syncthreads();
  if (found) atomicOr(&s, 1);
  __syncthreads();
  if (threadIdx.x == 0 && s) atomicOr(flag, 1);
}

__global__ __launch_bounds__(256) void lengths_kernel(
    const unsigned char* __restrict__ mb, const int* __restrict__ flag,
    int* __restrict__ lengths) {
  const int i = blockIdx.x * 256 + threadIdx.x;
  if (i >= NN) return;
  const int esz = (*flag) ? 1 : 4;
  int len = LL;
  for (int j = 1; j < LL; ++j) {
    if (mb[(size_t)(i * LL + j) * esz] != 0) { len = j; break; }
  }
  lengths[i] = len;
}

// ---------------------------------------------------------------------------
// prep: fp32 weights -> bf16 copies (with K-padding where needed)
// regions: qkvw[3*384*128] | outw[3*128*128] | projw->[128][192] pad |
//          w1 (x-part cols 0..255) -> [128][256] | w2[128][128]
// ---------------------------------------------------------------------------
__global__ __launch_bounds__(256) void prep_weights(
    const float* __restrict__ qkvw, const float* __restrict__ outw,
    const float* __restrict__ projw, const float* __restrict__ w1,
    const float* __restrict__ w2,
    unsigned short* __restrict__ qkvwbf, unsigned short* __restrict__ outwbf,
    unsigned short* __restrict__ projwbf, unsigned short* __restrict__ w1xbf,
    unsigned short* __restrict__ w2bf) {
  int i = blockIdx.x * 256 + threadIdx.x;
  const int n_qkv = 3 * 384 * 128, n_out = 3 * 128 * 128;
  const int n_proj = 128 * 192, n_w1 = 128 * 256, n_w2 = 128 * 128;
  if (i < n_qkv) { qkvwbf[i] = f2bf(qkvw[i]); return; }
  i -= n_qkv;
  if (i < n_out) { outwbf[i] = f2bf(outw[i]); return; }
  i -= n_out;
  if (i < n_proj) {
    int n = i / 192, c = i - n * 192;
    projwbf[i] = f2bf(c < 160 ? projw[n * 160 + c] : 0.f);
    return;
  }
  i -= n_proj;
  if (i < n_w1) {
    int n = i / 256, c = i - n * 256;
    w1xbf[i] = f2bf(w1[n * 258 + c]);
    return;
  }
  i -= n_w1;
  if (i < n_w2) w2bf[i] = f2bf(w2[i]);
}

// ---------------------------------------------------------------------------
// feat_build: bf16 feature matrix [NN][192]
// [type_emb(64) | cat0(32) | cat1(32) | relu(deg)(32) | zeros(32)]
// ---------------------------------------------------------------------------
__global__ __launch_bounds__(256) void feat_build(
    const int* __restrict__ ti, const int* __restrict__ ci,
    const float* __restrict__ ldg, const float* __restrict__ temb,
    const float* __restrict__ c0, const float* __restrict__ c1,
    const float* __restrict__ dw, const float* __restrict__ db,
    unsigned short* __restrict__ feat) {
  const int i = blockIdx.x * 256 + threadIdx.x;
  if (i >= NN * 192) return;
  const int n = i / 192, c = i - n * 192;
  float v;
  if (c < 64)       v = temb[(size_t)ti[n] * 64 + c];
  else if (c < 96)  v = c0[(size_t)ci[2 * n] * 32 + (c - 64)];
  else if (c < 128) v = c1[(size_t)ci[2 * n + 1] * 32 + (c - 96)];
  else if (c < 160) v = fmaxf(fmaf(ldg[n], dw[c - 128], db[c - 128]), 0.f);
  else              v = 0.f;
  feat[i] = f2bf(v);
}

// ---------------------------------------------------------------------------
// bf16 MFMA GEMM: C[M,NO] = act(A @ W^T + bias), 128x128 tile, BK=64.
// A: bf16 rows of a_rs bytes; W: bf16 [NO][K] rows of w_rs bytes.
// 4 waves in 2x2; per wave 64x64 via 4x4 frags of 16x16x32.
// LDS tiles [128 rows][128 B] with XOR-swizzle byte^((row&7)<<4), applied on
// the global SOURCE address (T2/m173) so global_load_lds dest stays linear.
// ---------------------------------------------------------------------------
__global__ __launch_bounds__(256) void mfma_gemm(
    const char* __restrict__ A, int a_rs, const char* __restrict__ W, int w_rs,
    const float* __restrict__ bias, int nsteps, int relu,
    unsigned short* __restrict__ C, int c_rs) {
  __shared__ char As[16384];
  __shared__ char Bs[16384];
  const int t = threadIdx.x, l = t & 63, w = t >> 6;
  const int bm = blockIdx.x * 128, bn = blockIdx.y * 128;
  const int wr = w >> 1, wc = w & 1;
  f32x4 acc[4][4];
#pragma unroll
  for (int mi = 0; mi < 4; ++mi)
#pragma unroll
    for (int ni = 0; ni < 4; ++ni)
#pragma unroll
      for (int j = 0; j < 4; ++j) acc[mi][ni][j] = 0.f;

  for (int ks = 0; ks < nsteps; ++ks) {
#pragma unroll
    for (int i = 0; i < 4; ++i) {
      const int row = w * 32 + i * 8 + (l >> 3);
      const int ch = (l & 7) ^ (row & 7);
      gload16(A + (size_t)(bm + row) * a_rs + ks * 128 + ch * 16,
              As + w * 4096 + i * 1024);
      gload16(W + (size_t)(bn + row) * w_rs + ks * 128 + ch * 16,
              Bs + w * 4096 + i * 1024);
    }
    __syncthreads();
#pragma unroll
    for (int k0 = 0; k0 < 2; ++k0) {
      bf16x8 af[4], bff[4];
#pragma unroll
      for (int mi = 0; mi < 4; ++mi) {
        const int r = wr * 64 + mi * 16 + (l & 15);
        const int off = (k0 * 64 + (l >> 4) * 16) ^ ((r & 7) << 4);
        af[mi] = *(const bf16x8*)(As + r * 128 + off);
      }
#pragma unroll
      for (int ni = 0; ni < 4; ++ni) {
        const int r = wc * 64 + ni * 16 + (l & 15);
        const int off = (k0 * 64 + (l >> 4) * 16) ^ ((r & 7) << 4);
        bff[ni] = *(const bf16x8*)(Bs + r * 128 + off);
      }
#pragma unroll
      for (int mi = 0; mi < 4; ++mi)
#pragma unroll
        for (int ni = 0; ni < 4; ++ni)
          acc[mi][ni] = __builtin_amdgcn_mfma_f32_16x16x32_bf16(
              af[mi], bff[ni], acc[mi][ni], 0, 0, 0);
    }
    __syncthreads();
  }
  // epilogue: C/D layout col=lane&15, row=(lane>>4)*4+j
#pragma unroll
  for (int ni = 0; ni < 4; ++ni) {
    const int col = bn + wc * 64 + ni * 16 + (l & 15);
    const float bz = bias[col];
#pragma unroll
    for (int mi = 0; mi < 4; ++mi)
#pragma unroll
      for (int j = 0; j < 4; ++j) {
        const int row = bm + wr * 64 + mi * 16 + (l >> 4) * 4 + j;
        float v = acc[mi][ni][j] + bz;
        if (relu) v = fmaxf(v, 0.f);
        C[(size_t)row * c_rs + col] = f2bf(v);
      }
  }
}

// ---------------------------------------------------------------------------
// Attention on bf16 QKV [N][384]: wave per node, fp32 math.
// ---------------------------------------------------------------------------
__global__ __launch_bounds__(256) void attn_kernel(
    const unsigned short* __restrict__ QKV, const int* __restrict__ ctx,
    const int* __restrict__ lengths, unsigned short* __restrict__ O) {
  __shared__ int s_idx[4][33];
  __shared__ float s_p[4][4][33];
  const int t = threadIdx.x;
  const int w = t >> 6;
  const int lane = t & 63;
  const int node = blockIdx.x * 4 + w;
  const int len = lengths[node];
  if (lane < LL) s_idx[w][lane] = ctx[(size_t)node * LL + lane];
  const unsigned int qu = *(const unsigned int*)(QKV + (size_t)node * 384 + 2 * lane);
  const float qx = bf2f((unsigned short)qu), qy = bf2f((unsigned short)(qu >> 16));
  __syncthreads();
  const int h = lane >> 4;
  for (int l = 0; l < len; ++l) {
    const int ki = s_idx[w][l];
    const unsigned int ku = *(const unsigned int*)(QKV + (size_t)ki * 384 + 128 + 2 * lane);
    float part = qx * bf2f((unsigned short)ku) + qy * bf2f((unsigned short)(ku >> 16));
    part += __shfl_xor(part, 1);
    part += __shfl_xor(part, 2);
    part += __shfl_xor(part, 4);
    part += __shfl_xor(part, 8);
    if ((lane & 15) == 0) s_p[w][h][l] = part * 0.17677669529663687f;
  }
  __syncthreads();
#pragma unroll
  for (int hh = 0; hh < 4; ++hh) {
    float s = -INFINITY;
    if (lane < len) s = s_p[w][hh][lane];
    float m = s;
    m = fmaxf(m, __shfl_xor(m, 1));
    m = fmaxf(m, __shfl_xor(m, 2));
    m = fmaxf(m, __shfl_xor(m, 4));
    m = fmaxf(m, __shfl_xor(m, 8));
    m = fmaxf(m, __shfl_xor(m, 16));
    m = fmaxf(m, __shfl_xor(m, 32));
    float e = (lane < len) ? __expf(s - m) : 0.f;
    float sum = e;
    sum += __shfl_xor(sum, 1);
    sum += __shfl_xor(sum, 2);
    sum += __shfl_xor(sum, 4);
    sum += __shfl_xor(sum, 8);
    sum += __shfl_xor(sum, 16);
    sum += __shfl_xor(sum, 32);
    if (lane < LL) s_p[w][hh][lane] = e / sum;
  }
  __syncthreads();
  float ox = 0.f, oy = 0.f;
  for (int l = 0; l < len; ++l) {
    const float p = s_p[w][h][l];
    const int vi = s_idx[w][l];
    const unsigned int vu = *(const unsigned int*)(QKV + (size_t)vi * 384 + 256 + 2 * lane);
    ox = fmaf(p, bf2f((unsigned short)vu), ox);
    oy = fmaf(p, bf2f((unsigned short)(vu >> 16)), oy);
  }
  const unsigned int ou = ((unsigned int)f2bf(oy) << 16) | f2bf(ox);
  *(unsigned int*)(O + (size_t)node * DD + 2 * lane) = ou;
}

// ---------------------------------------------------------------------------
// Fused edge MLP, 128 edges/block, all-MFMA:
// phase1: h1 = relu([x_u|x_v] @ W1x^T + ef-fixup(fp32) + b1) -> bf16 LDS (swz)
// phase2: h2acc = h1 @ W2^T (MFMA)
// phase3: logit = sum relu(h2+b2)*w3 + b3 (fp32, deterministic LDS partials)
// ---------------------------------------------------------------------------
__global__ __launch_bounds__(256) void edge_fused(
    const char* __restrict__ xbf, const int* __restrict__ eu,
    const int* __restrict__ ev, const float* __restrict__ ef,
    const char* __restrict__ w1x, const float* __restrict__ w1f,
    const float* __restrict__ b1, const char* __restrict__ w2,
    const float* __restrict__ b2, const float* __restrict__ w3,
    const float* __restrict__ b3, float* __restrict__ out) {
  __shared__ char lds[65536];
  char* As = lds;                // 16 KB (phase1 A; phase3 partials overlay)
  char* Bs = lds + 16384;        // 16 KB (W1x slice, then W2 slices)
  char* H1 = lds + 32768;        // 32 KB bf16 [128][256B] swizzled
  float* s_part = (float*)lds;   // [2][128], used after As is dead
  const int t = threadIdx.x, l = t & 63, w = t >> 6;
  const int bm = blockIdx.x * 128;
  const int wr = w >> 1, wc = w & 1;
  f32x4 acc[4][4];
#pragma unroll
  for (int mi = 0; mi < 4; ++mi)
#pragma unroll
    for (int ni = 0; ni < 4; ++ni)
#pragma unroll
      for (int j = 0; j < 4; ++j) acc[mi][ni][j] = 0.f;

  for (int ks = 0; ks < 4; ++ks) {
    const int* idxp = (ks < 2) ? eu : ev;
#pragma unroll
    for (int i = 0; i < 4; ++i) {
      const int row = w * 32 + i * 8 + (l >> 3);
      const int ch = (l & 7) ^ (row & 7);
      const int nidx = idxp[bm + row];
      gload16(xbf + (size_t)nidx * 256 + (ks & 1) * 128 + ch * 16,
              As + w * 4096 + i * 1024);
      gload16(w1x + (size_t)row * 512 + ks * 128 + ch * 16,
              Bs + w * 4096 + i * 1024);
    }
    __syncthreads();
#pragma unroll
    for (int k0 = 0; k0 < 2; ++k0) {
      bf16x8 af[4], bff[4];
#pragma unroll
      for (int mi = 0; mi < 4; ++mi) {
        const int r = wr * 64 + mi * 16 + (l & 15);
        const int off = (k0 * 64 + (l >> 4) * 16) ^ ((r & 7) << 4);
        af[mi] = *(const bf16x8*)(As + r * 128 + off);
      }
#pragma unroll
      for (int ni = 0; ni < 4; ++ni) {
        const int r = wc * 64 + ni * 16 + (l & 15);
        const int off = (k0 * 64 + (l >> 4) * 16) ^ ((r & 7) << 4);
        bff[ni] = *(const bf16x8*)(Bs + r * 128 + off);
      }
#pragma unroll
      for (int mi = 0; mi < 4; ++mi)
#pragma unroll
        for (int ni = 0; ni < 4; ++ni)
          acc[mi][ni] = __builtin_amdgcn_mfma_f32_16x16x32_bf16(
              af[mi], bff[ni], acc[mi][ni], 0, 0, 0);
    }
    __syncthreads();
  }
  // fp32 ef fixup (k=256,257) + bias + relu -> H1 bf16 (swizzled)
  float w1c0[4], w1c1[4], bb[4];
#pragma unroll
  for (int ni = 0; ni < 4; ++ni) {
    const int col = wc * 64 + ni * 16 + (l & 15);
    w1c0[ni] = w1f[col * 258 + 256];
    w1c1[ni] = w1f[col * 258 + 257];
    bb[ni] = b1[col];
  }
#pragma unroll
  for (int mi = 0; mi < 4; ++mi)
#pragma unroll
    for (int j = 0; j < 4; ++j) {
      const int rl = wr * 64 + mi * 16 + (l >> 4) * 4 + j;
      const float2 e2 = *(const float2*)(ef + 2 * (size_t)(bm + rl));
#pragma unroll
      for (int ni = 0; ni < 4; ++ni) {
        float v = acc[mi][ni][j] + e2.x * w1c0[ni] + e2.y * w1c1[ni] + bb[ni];
        v = fmaxf(v, 0.f);
        const int col = wc * 64 + ni * 16 + (l & 15);
        const int off = (col * 2) ^ ((rl & 7) << 4);
        *(unsigned short*)(H1 + rl * 256 + off) = f2bf(v);
      }
    }
  __syncthreads();
  f32x4 acc2[4][4];
#pragma unroll
  for (int mi = 0; mi < 4; ++mi)
#pragma unroll
    for (int ni = 0; ni < 4; ++ni)
#pragma unroll
      for (int j = 0; j < 4; ++j) acc2[mi][ni][j] = 0.f;
  for (int ks2 = 0; ks2 < 2; ++ks2) {
#pragma unroll
    for (int i = 0; i < 4; ++i) {
      const int row = w * 32 + i * 8 + (l >> 3);
      const int ch = (l & 7) ^ (row & 7);
      gload16(w2 + (size_t)row * 256 + ks2 * 128 + ch * 16,
              Bs + w * 4096 + i * 1024);
    }
    __syncthreads();
#pragma unroll
    for (int k0 = 0; k0 < 2; ++k0) {
      bf16x8 af[4], bff[4];
#pragma unroll
      for (int mi = 0; mi < 4; ++mi) {
        const int r = wr * 64 + mi * 16 + (l & 15);
        const int off = (ks2 * 128 + k0 * 64 + (l >> 4) * 16) ^ ((r & 7) << 4);
        af[mi] = *(const bf16x8*)(H1 + r * 256 + off);
      }
#pragma unroll
      for (int ni = 0; ni < 4; ++ni) {
        const int r = wc * 64 + ni * 16 + (l & 15);
        const int off = (k0 * 64 + (l >> 4) * 16) ^ ((r & 7) << 4);
        bff[ni] = *(const bf16x8*)(Bs + r * 128 + off);
      }
#pragma unroll
      for (int mi = 0; mi < 4; ++mi)
#pragma unroll
        for (int ni = 0; ni < 4; ++ni)
          acc2[mi][ni] = __builtin_amdgcn_mfma_f32_16x16x32_bf16(
              af[mi], bff[ni], acc2[mi][ni], 0, 0, 0);
    }
    __syncthreads();
  }
  // phase 3: relu(h2+b2)*w3, fp32, deterministic partials
  float b2v[4], w3v[4];
#pragma unroll
  for (int ni = 0; ni < 4; ++ni) {
    const int col = wc * 64 + ni * 16 + (l & 15);
    b2v[ni] = b2[col];
    w3v[ni] = w3[col];
  }
#pragma unroll
  for (int mi = 0; mi < 4; ++mi)
#pragma unroll
    for (int j = 0; j < 4; ++j) {
      const int rl = wr * 64 + mi * 16 + (l >> 4) * 4 + j;
      float p = 0.f;
#pragma unroll
      for (int ni = 0; ni < 4; ++ni) {
        const float h2 = fmaxf(acc2[mi][ni][j] + b2v[ni], 0.f);
        p = fmaf(h2, w3v[ni], p);
      }
      p += __shfl_xor(p, 1);
      p += __shfl_xor(p, 2);
      p += __shfl_xor(p, 4);
      p += __shfl_xor(p, 8);
      if ((l & 15) == 0) s_part[wc * 128 + rl] = p;
    }
  __syncthreads();
  if (t < 128) out[bm + t] = s_part[t] + s_part[128 + t] + b3[0];
}

// ---------------------------------------------------------------------------
extern "C" void kernel_launch(void* const* d_in, const int* in_sizes, int n_in,
                              void* d_out, int out_size, void* d_ws, size_t ws_size,
                              hipStream_t stream) {
  (void)in_sizes; (void)n_in; (void)out_size; (void)ws_size;
  const int*   type_idx   = (const int*)d_in[0];
  const int*   cat_idx    = (const int*)d_in[1];
  const float* log_degree = (const float*)d_in[2];
  const int*   ctx        = (const int*)d_in[3];
  const unsigned char* mask = (const unsigned char*)d_in[4];
  const int*   eu         = (const int*)d_in[5];
  const int*   ev         = (const int*)d_in[6];
  const float* ef         = (const float*)d_in[7];
  const float* type_embed = (const float*)d_in[8];
  const float* cat0       = (const float*)d_in[9];
  const float* cat1       = (const float*)d_in[10];
  const float* dw         = (const float*)d_in[11];
  const float* db         = (const float*)d_in[12];
  const float* proj_w     = (const float*)d_in[13];
  const float* proj_b     = (const float*)d_in[14];
  const float* qkv_w      = (const float*)d_in[15];
  const float* qkv_b      = (const float*)d_in[16];
  const float* out_w      = (const float*)d_in[17];
  const float* out_b      = (const float*)d_in[18];
  const float* w1         = (const float*)d_in[19];
  const float* b1         = (const float*)d_in[20];
  const float* w2         = (const float*)d_in[21];
  const float* b2         = (const float*)d_in[22];
  const float* w3         = (const float*)d_in[23];
  const float* b3         = (const float*)d_in[24];

  char* ws = (char*)d_ws;
  char* xbf     = ws;                       // [N][128] bf16   8 MB
  char* qkvbf   = ws + 8388608;             // [N][384] bf16   24 MB
  char* obf     = ws + 33554432;            // [N][128] bf16   8 MB
  char* featbf  = ws + 41943040;            // [N][192] bf16   12 MB
  char* qkvwbf  = ws + 54525952;            // 3*384*128 bf16
  char* outwbf  = ws + 54820864;            // 3*128*128 bf16
  char* projwbf = ws + 54919168;            // 128*192 bf16
  char* w1xbf   = ws + 54968320;            // 128*256 bf16
  char* w2bf    = ws + 55033856;            // 128*128 bf16
  int*  lengths = (int*)(ws + 55066624);
  int*  flag    = (int*)(ws + 55197696);

  hipMemsetAsync(flag, 0, sizeof(int), stream);
  detect_mask_kernel<<<256, 256, 0, stream>>>((const unsigned int*)mask, flag);
  lengths_kernel<<<NN / 256, 256, 0, stream>>>(mask, flag, lengths);

  prep_weights<<<1056, 256, 0, stream>>>(
      qkv_w, out_w, proj_w, w1, w2,
      (unsigned short*)qkvwbf, (unsigned short*)outwbf,
      (unsigned short*)projwbf, (unsigned short*)w1xbf, (unsigned short*)w2bf);
  feat_build<<<NN * 192 / 256, 256, 0, stream>>>(
      type_idx, cat_idx, log_degree, type_embed, cat0, cat1, dw, db,
      (unsigned short*)featbf);

  // encode: x = feat[192] @ projw^T + proj_b (no relu)
  mfma_gemm<<<dim3(NN / 128, 1), 256, 0, stream>>>(
      featbf, 384, projwbf, 384, proj_b, 3, 0, (unsigned short*)xbf, 128);

  for (int layer = 0; layer < 3; ++layer) {
    mfma_gemm<<<dim3(NN / 128, 3), 256, 0, stream>>>(
        xbf, 256, qkvwbf + (size_t)layer * 98304, 256,
        qkv_b + (size_t)layer * 384, 2, 0, (unsigned short*)qkvbf, 384);
    attn_kernel<<<NN / 4, 256, 0, stream>>>(
        (const unsigned short*)qkvbf, ctx, lengths, (unsigned short*)obf);
    mfma_gemm<<<dim3(NN / 128, 1), 256, 0, stream>>>(
        obf, 256, outwbf + (size_t)layer * 32768, 256,
        out_b + (size_t)layer * 128, 2, 1, (unsigned short*)xbf, 128);
  }

  edge_fused<<<EE / 128, 256, 0, stream>>>(
      xbf, eu, ev, ef, w1xbf, w1, b1, w2bf, b2, w3, b3, (float*)d_out);
}

// Round 5
// 259.115 us; speedup vs baseline: 7.0457x; 1.5470x over previous
//
#include <hip/hip_runtime.h>
#include <hip/hip_bf16.h>
#include <math.h>

#define NN 32768
#define LL 33
#define DD 128
#define EE 131072

typedef short bf16x8 __attribute__((ext_vector_type(8)));
typedef float f32x4 __attribute__((ext_vector_type(4)));

__device__ inline unsigned short f2bf(float f) {
  __hip_bfloat16 h = __float2bfloat16(f);
  return *reinterpret_cast<unsigned short*>(&h);
}
__device__ inline float bf2f(unsigned short u) {
  return __uint_as_float(((unsigned int)u) << 16);
}
// async global->LDS, 16B per lane. LDS dest is wave-uniform base + lane*16;
// global src is per-lane (we pre-swizzle the SOURCE so LDS stays linear).
__device__ inline void gload16(const void* g, void* lds) {
  __builtin_amdgcn_global_load_lds(
      (const __attribute__((address_space(1))) unsigned int*)g,
      (__attribute__((address_space(3))) unsigned int*)lds, 16, 0, 0);
}

// ---------------------------------------------------------------------------
// Parallel mask-layout detect. Reads the first NN*LL bytes (safe under both
// layouts) as dwords; a nonzero byte at p%4!=0 <=> (dword & 0xFFFFFF00) != 0
// <=> byte-layout mask. flag must be zeroed beforehand (hipMemsetAsync).
// ---------------------------------------------------------------------------
__global__ __launch_bounds__(256) void detect_mask_kernel(
    const unsigned int* __restrict__ mw, int* __restrict__ flag) {
  const int nd = NN * LL / 4;
  int found = 0;
  for (int p = blockIdx.x * 256 + threadIdx.x; p < nd; p += gridDim.x * 256) {
    if (mw[p] & 0xFFFFFF00u) found = 1;
  }
  __shared__ int s;
  if (threadIdx.x == 0) s = 0;
  __syncthreads();
  if (found) atomicOr(&s, 1);
  __syncthreads();
  if (threadIdx.x == 0 && s) atomicOr(flag, 1);
}

__global__ __launch_bounds__(256) void lengths_kernel(
    const unsigned char* __restrict__ mb, const int* __restrict__ flag,
    int* __restrict__ lengths) {
  const int i = blockIdx.x * 256 + threadIdx.x;
  if (i >= NN) return;
  const int esz = (*flag) ? 1 : 4;
  int len = LL;
  for (int j = 1; j < LL; ++j) {
    if (mb[(size_t)(i * LL + j) * esz] != 0) { len = j; break; }
  }
  lengths[i] = len;
}

// ---------------------------------------------------------------------------
// prep: fp32 weights -> bf16 copies (with K-padding where needed)
// ---------------------------------------------------------------------------
__global__ __launch_bounds__(256) void prep_weights(
    const float* __restrict__ qkvw, const float* __restrict__ outw,
    const float* __restrict__ projw, const float* __restrict__ w1,
    const float* __restrict__ w2,
    unsigned short* __restrict__ qkvwbf, unsigned short* __restrict__ outwbf,
    unsigned short* __restrict__ projwbf, unsigned short* __restrict__ w1xbf,
    unsigned short* __restrict__ w2bf) {
  int i = blockIdx.x * 256 + threadIdx.x;
  const int n_qkv = 3 * 384 * 128, n_out = 3 * 128 * 128;
  const int n_proj = 128 * 192, n_w1 = 128 * 256, n_w2 = 128 * 128;
  if (i < n_qkv) { qkvwbf[i] = f2bf(qkvw[i]); return; }
  i -= n_qkv;
  if (i < n_out) { outwbf[i] = f2bf(outw[i]); return; }
  i -= n_out;
  if (i < n_proj) {
    int n = i / 192, c = i - n * 192;
    projwbf[i] = f2bf(c < 160 ? projw[n * 160 + c] : 0.f);
    return;
  }
  i -= n_proj;
  if (i < n_w1) {
    int n = i / 256, c = i - n * 256;
    w1xbf[i] = f2bf(w1[n * 258 + c]);
    return;
  }
  i -= n_w1;
  if (i < n_w2) w2bf[i] = f2bf(w2[i]);
}

// ---------------------------------------------------------------------------
// feat_build: bf16 feature matrix [NN][192]
// ---------------------------------------------------------------------------
__global__ __launch_bounds__(256) void feat_build(
    const int* __restrict__ ti, const int* __restrict__ ci,
    const float* __restrict__ ldg, const float* __restrict__ temb,
    const float* __restrict__ c0, const float* __restrict__ c1,
    const float* __restrict__ dw, const float* __restrict__ db,
    unsigned short* __restrict__ feat) {
  const int i = blockIdx.x * 256 + threadIdx.x;
  if (i >= NN * 192) return;
  const int n = i / 192, c = i - n * 192;
  float v;
  if (c < 64)       v = temb[(size_t)ti[n] * 64 + c];
  else if (c < 96)  v = c0[(size_t)ci[2 * n] * 32 + (c - 64)];
  else if (c < 128) v = c1[(size_t)ci[2 * n + 1] * 32 + (c - 96)];
  else if (c < 160) v = fmaxf(fmaf(ldg[n], dw[c - 128], db[c - 128]), 0.f);
  else              v = 0.f;
  feat[i] = f2bf(v);
}

// ---------------------------------------------------------------------------
// bf16 MFMA GEMM: C[M,NO] = act(A @ W^T + bias), 128x128 tile, BK=64.
// seg != 0: y-block outputs go to planar segments C + y*seg (local col),
// giving planar Q/K/V buffers for gather locality.
// ---------------------------------------------------------------------------
__global__ __launch_bounds__(256) void mfma_gemm(
    const char* __restrict__ A, int a_rs, const char* __restrict__ W, int w_rs,
    const float* __restrict__ bias, int nsteps, int relu,
    unsigned short* __restrict__ C, int c_rs, size_t seg) {
  __shared__ char As[16384];
  __shared__ char Bs[16384];
  const int t = threadIdx.x, l = t & 63, w = t >> 6;
  const int bm = blockIdx.x * 128, bn = blockIdx.y * 128;
  const int wr = w >> 1, wc = w & 1;
  f32x4 acc[4][4];
#pragma unroll
  for (int mi = 0; mi < 4; ++mi)
#pragma unroll
    for (int ni = 0; ni < 4; ++ni)
#pragma unroll
      for (int j = 0; j < 4; ++j) acc[mi][ni][j] = 0.f;

  for (int ks = 0; ks < nsteps; ++ks) {
#pragma unroll
    for (int i = 0; i < 4; ++i) {
      const int row = w * 32 + i * 8 + (l >> 3);
      const int ch = (l & 7) ^ (row & 7);
      gload16(A + (size_t)(bm + row) * a_rs + ks * 128 + ch * 16,
              As + w * 4096 + i * 1024);
      gload16(W + (size_t)(bn + row) * w_rs + ks * 128 + ch * 16,
              Bs + w * 4096 + i * 1024);
    }
    __syncthreads();
#pragma unroll
    for (int k0 = 0; k0 < 2; ++k0) {
      bf16x8 af[4], bff[4];
#pragma unroll
      for (int mi = 0; mi < 4; ++mi) {
        const int r = wr * 64 + mi * 16 + (l & 15);
        const int off = (k0 * 64 + (l >> 4) * 16) ^ ((r & 7) << 4);
        af[mi] = *(const bf16x8*)(As + r * 128 + off);
      }
#pragma unroll
      for (int ni = 0; ni < 4; ++ni) {
        const int r = wc * 64 + ni * 16 + (l & 15);
        const int off = (k0 * 64 + (l >> 4) * 16) ^ ((r & 7) << 4);
        bff[ni] = *(const bf16x8*)(Bs + r * 128 + off);
      }
#pragma unroll
      for (int mi = 0; mi < 4; ++mi)
#pragma unroll
        for (int ni = 0; ni < 4; ++ni)
          acc[mi][ni] = __builtin_amdgcn_mfma_f32_16x16x32_bf16(
              af[mi], bff[ni], acc[mi][ni], 0, 0, 0);
    }
    __syncthreads();
  }
  unsigned short* Cw = C;
  int coloff = bn;
  if (seg) { Cw = C + (size_t)blockIdx.y * seg; coloff = 0; }
#pragma unroll
  for (int ni = 0; ni < 4; ++ni) {
    const int lc = wc * 64 + ni * 16 + (l & 15);
    const float bz = bias[bn + lc];
    const int col = coloff + lc;
#pragma unroll
    for (int mi = 0; mi < 4; ++mi)
#pragma unroll
      for (int j = 0; j < 4; ++j) {
        const int row = bm + wr * 64 + mi * 16 + (l >> 4) * 4 + j;
        float v = acc[mi][ni][j] + bz;
        if (relu) v = fmaxf(v, 0.f);
        Cw[(size_t)row * c_rs + col] = f2bf(v);
      }
  }
}

// ---------------------------------------------------------------------------
// Attention, planar Q/K/V [N][128] bf16, single-pass online softmax.
// Wave per node; lane covers dims {2*lane, 2*lane+1}; head = lane>>4.
// Chunk-4 unroll: 8 predicated loads in flight per chunk.
// ---------------------------------------------------------------------------
__global__ __launch_bounds__(256) void attn_kernel(
    const unsigned short* __restrict__ Q, const unsigned short* __restrict__ K,
    const unsigned short* __restrict__ V, const int* __restrict__ ctx,
    const int* __restrict__ lengths, unsigned short* __restrict__ O) {
  __shared__ int s_idx[4][36];
  const int t = threadIdx.x;
  const int w = t >> 6;
  const int lane = t & 63;
  const int node = blockIdx.x * 4 + w;
  const int len = lengths[node];
  if (lane < LL) s_idx[w][lane] = ctx[(size_t)node * LL + lane];
  const unsigned int qu = *(const unsigned int*)(Q + (size_t)node * 128 + 2 * lane);
  const float qx = bf2f((unsigned short)qu) * 0.17677669529663687f;  // 1/sqrt(32)
  const float qy = bf2f((unsigned short)(qu >> 16)) * 0.17677669529663687f;
  __syncthreads();
  float m = -INFINITY, ssum = 0.f, ax = 0.f, ay = 0.f;
  for (int l0 = 0; l0 < len; l0 += 4) {
    unsigned int ku[4], vu[4];
    int valid[4];
#pragma unroll
    for (int c = 0; c < 4; ++c) {
      const int lc = l0 + c;
      const int ok = lc < len;
      valid[c] = ok;
      const int ki = s_idx[w][ok ? lc : 0];
      ku[c] = *(const unsigned int*)(K + (size_t)ki * 128 + 2 * lane);
      vu[c] = *(const unsigned int*)(V + (size_t)ki * 128 + 2 * lane);
    }
#pragma unroll
    for (int c = 0; c < 4; ++c) {
      float part = qx * bf2f((unsigned short)ku[c]) +
                   qy * bf2f((unsigned short)(ku[c] >> 16));
      part += __shfl_xor(part, 1);
      part += __shfl_xor(part, 2);
      part += __shfl_xor(part, 4);
      part += __shfl_xor(part, 8);
      const float s = valid[c] ? part : -INFINITY;
      const float mnew = fmaxf(m, s);
      const float r = __expf(m - mnew);   // first iter: exp(-inf)=0
      const float e = __expf(s - mnew);
      ssum = fmaf(ssum, r, e);
      ax = fmaf(e, bf2f((unsigned short)vu[c]), ax * r);
      ay = fmaf(e, bf2f((unsigned short)(vu[c] >> 16)), ay * r);
      m = mnew;
    }
  }
  const float inv = 1.f / ssum;
  const unsigned int ou =
      ((unsigned int)f2bf(ay * inv) << 16) | f2bf(ax * inv);
  *(unsigned int*)(O + (size_t)node * DD + 2 * lane) = ou;
}

// ---------------------------------------------------------------------------
// Fused edge MLP, 128 edges/block, all-MFMA (unchanged from round 3).
// ---------------------------------------------------------------------------
__global__ __launch_bounds__(256) void edge_fused(
    const char* __restrict__ xbf, const int* __restrict__ eu,
    const int* __restrict__ ev, const float* __restrict__ ef,
    const char* __restrict__ w1x, const float* __restrict__ w1f,
    const float* __restrict__ b1, const char* __restrict__ w2,
    const float* __restrict__ b2, const float* __restrict__ w3,
    const float* __restrict__ b3, float* __restrict__ out) {
  __shared__ char lds[65536];
  char* As = lds;
  char* Bs = lds + 16384;
  char* H1 = lds + 32768;
  float* s_part = (float*)lds;
  const int t = threadIdx.x, l = t & 63, w = t >> 6;
  const int bm = blockIdx.x * 128;
  const int wr = w >> 1, wc = w & 1;
  f32x4 acc[4][4];
#pragma unroll
  for (int mi = 0; mi < 4; ++mi)
#pragma unroll
    for (int ni = 0; ni < 4; ++ni)
#pragma unroll
      for (int j = 0; j < 4; ++j) acc[mi][ni][j] = 0.f;

  for (int ks = 0; ks < 4; ++ks) {
    const int* idxp = (ks < 2) ? eu : ev;
#pragma unroll
    for (int i = 0; i < 4; ++i) {
      const int row = w * 32 + i * 8 + (l >> 3);
      const int ch = (l & 7) ^ (row & 7);
      const int nidx = idxp[bm + row];
      gload16(xbf + (size_t)nidx * 256 + (ks & 1) * 128 + ch * 16,
              As + w * 4096 + i * 1024);
      gload16(w1x + (size_t)row * 512 + ks * 128 + ch * 16,
              Bs + w * 4096 + i * 1024);
    }
    __syncthreads();
#pragma unroll
    for (int k0 = 0; k0 < 2; ++k0) {
      bf16x8 af[4], bff[4];
#pragma unroll
      for (int mi = 0; mi < 4; ++mi) {
        const int r = wr * 64 + mi * 16 + (l & 15);
        const int off = (k0 * 64 + (l >> 4) * 16) ^ ((r & 7) << 4);
        af[mi] = *(const bf16x8*)(As + r * 128 + off);
      }
#pragma unroll
      for (int ni = 0; ni < 4; ++ni) {
        const int r = wc * 64 + ni * 16 + (l & 15);
        const int off = (k0 * 64 + (l >> 4) * 16) ^ ((r & 7) << 4);
        bff[ni] = *(const bf16x8*)(Bs + r * 128 + off);
      }
#pragma unroll
      for (int mi = 0; mi < 4; ++mi)
#pragma unroll
        for (int ni = 0; ni < 4; ++ni)
          acc[mi][ni] = __builtin_amdgcn_mfma_f32_16x16x32_bf16(
              af[mi], bff[ni], acc[mi][ni], 0, 0, 0);
    }
    __syncthreads();
  }
  float w1c0[4], w1c1[4], bb[4];
#pragma unroll
  for (int ni = 0; ni < 4; ++ni) {
    const int col = wc * 64 + ni * 16 + (l & 15);
    w1c0[ni] = w1f[col * 258 + 256];
    w1c1[ni] = w1f[col * 258 + 257];
    bb[ni] = b1[col];
  }
#pragma unroll
  for (int mi = 0; mi < 4; ++mi)
#pragma unroll
    for (int j = 0; j < 4; ++j) {
      const int rl = wr * 64 + mi * 16 + (l >> 4) * 4 + j;
      const float2 e2 = *(const float2*)(ef + 2 * (size_t)(bm + rl));
#pragma unroll
      for (int ni = 0; ni < 4; ++ni) {
        float v = acc[mi][ni][j] + e2.x * w1c0[ni] + e2.y * w1c1[ni] + bb[ni];
        v = fmaxf(v, 0.f);
        const int col = wc * 64 + ni * 16 + (l & 15);
        const int off = (col * 2) ^ ((rl & 7) << 4);
        *(unsigned short*)(H1 + rl * 256 + off) = f2bf(v);
      }
    }
  __syncthreads();
  f32x4 acc2[4][4];
#pragma unroll
  for (int mi = 0; mi < 4; ++mi)
#pragma unroll
    for (int ni = 0; ni < 4; ++ni)
#pragma unroll
      for (int j = 0; j < 4; ++j) acc2[mi][ni][j] = 0.f;
  for (int ks2 = 0; ks2 < 2; ++ks2) {
#pragma unroll
    for (int i = 0; i < 4; ++i) {
      const int row = w * 32 + i * 8 + (l >> 3);
      const int ch = (l & 7) ^ (row & 7);
      gload16(w2 + (size_t)row * 256 + ks2 * 128 + ch * 16,
              Bs + w * 4096 + i * 1024);
    }
    __syncthreads();
#pragma unroll
    for (int k0 = 0; k0 < 2; ++k0) {
      bf16x8 af[4], bff[4];
#pragma unroll
      for (int mi = 0; mi < 4; ++mi) {
        const int r = wr * 64 + mi * 16 + (l & 15);
        const int off = (ks2 * 128 + k0 * 64 + (l >> 4) * 16) ^ ((r & 7) << 4);
        af[mi] = *(const bf16x8*)(H1 + r * 256 + off);
      }
#pragma unroll
      for (int ni = 0; ni < 4; ++ni) {
        const int r = wc * 64 + ni * 16 + (l & 15);
        const int off = (k0 * 64 + (l >> 4) * 16) ^ ((r & 7) << 4);
        bff[ni] = *(const bf16x8*)(Bs + r * 128 + off);
      }
#pragma unroll
      for (int mi = 0; mi < 4; ++mi)
#pragma unroll
        for (int ni = 0; ni < 4; ++ni)
          acc2[mi][ni] = __builtin_amdgcn_mfma_f32_16x16x32_bf16(
              af[mi], bff[ni], acc2[mi][ni], 0, 0, 0);
    }
    __syncthreads();
  }
  float b2v[4], w3v[4];
#pragma unroll
  for (int ni = 0; ni < 4; ++ni) {
    const int col = wc * 64 + ni * 16 + (l & 15);
    b2v[ni] = b2[col];
    w3v[ni] = w3[col];
  }
#pragma unroll
  for (int mi = 0; mi < 4; ++mi)
#pragma unroll
    for (int j = 0; j < 4; ++j) {
      const int rl = wr * 64 + mi * 16 + (l >> 4) * 4 + j;
      float p = 0.f;
#pragma unroll
      for (int ni = 0; ni < 4; ++ni) {
        const float h2 = fmaxf(acc2[mi][ni][j] + b2v[ni], 0.f);
        p = fmaf(h2, w3v[ni], p);
      }
      p += __shfl_xor(p, 1);
      p += __shfl_xor(p, 2);
      p += __shfl_xor(p, 4);
      p += __shfl_xor(p, 8);
      if ((l & 15) == 0) s_part[wc * 128 + rl] = p;
    }
  __syncthreads();
  if (t < 128) out[bm + t] = s_part[t] + s_part[128 + t] + b3[0];
}

// ---------------------------------------------------------------------------
extern "C" void kernel_launch(void* const* d_in, const int* in_sizes, int n_in,
                              void* d_out, int out_size, void* d_ws, size_t ws_size,
                              hipStream_t stream) {
  (void)in_sizes; (void)n_in; (void)out_size; (void)ws_size;
  const int*   type_idx   = (const int*)d_in[0];
  const int*   cat_idx    = (const int*)d_in[1];
  const float* log_degree = (const float*)d_in[2];
  const int*   ctx        = (const int*)d_in[3];
  const unsigned char* mask = (const unsigned char*)d_in[4];
  const int*   eu         = (const int*)d_in[5];
  const int*   ev         = (const int*)d_in[6];
  const float* ef         = (const float*)d_in[7];
  const float* type_embed = (const float*)d_in[8];
  const float* cat0       = (const float*)d_in[9];
  const float* cat1       = (const float*)d_in[10];
  const float* dw         = (const float*)d_in[11];
  const float* db         = (const float*)d_in[12];
  const float* proj_w     = (const float*)d_in[13];
  const float* proj_b     = (const float*)d_in[14];
  const float* qkv_w      = (const float*)d_in[15];
  const float* qkv_b      = (const float*)d_in[16];
  const float* out_w      = (const float*)d_in[17];
  const float* out_b      = (const float*)d_in[18];
  const float* w1         = (const float*)d_in[19];
  const float* b1         = (const float*)d_in[20];
  const float* w2         = (const float*)d_in[21];
  const float* b2         = (const float*)d_in[22];
  const float* w3         = (const float*)d_in[23];
  const float* b3         = (const float*)d_in[24];

  char* ws = (char*)d_ws;
  char* xbf     = ws;                       // [N][128] bf16   8 MB
  char* qkvbf   = ws + 8388608;             // [3][N][128] bf16 24 MB (planar)
  char* obf     = ws + 33554432;            // [N][128] bf16   8 MB
  char* featbf  = ws + 41943040;            // [N][192] bf16   12 MB
  char* qkvwbf  = ws + 54525952;            // 3*384*128 bf16
  char* outwbf  = ws + 54820864;            // 3*128*128 bf16
  char* projwbf = ws + 54919168;            // 128*192 bf16
  char* w1xbf   = ws + 54968320;            // 128*256 bf16
  char* w2bf    = ws + 55033856;            // 128*128 bf16
  int*  lengths = (int*)(ws + 55066624);
  int*  flag    = (int*)(ws + 55197696);

  hipMemsetAsync(flag, 0, sizeof(int), stream);
  detect_mask_kernel<<<256, 256, 0, stream>>>((const unsigned int*)mask, flag);
  lengths_kernel<<<NN / 256, 256, 0, stream>>>(mask, flag, lengths);

  prep_weights<<<1056, 256, 0, stream>>>(
      qkv_w, out_w, proj_w, w1, w2,
      (unsigned short*)qkvwbf, (unsigned short*)outwbf,
      (unsigned short*)projwbf, (unsigned short*)w1xbf, (unsigned short*)w2bf);
  feat_build<<<NN * 192 / 256, 256, 0, stream>>>(
      type_idx, cat_idx, log_degree, type_embed, cat0, cat1, dw, db,
      (unsigned short*)featbf);

  // encode: x = feat[192] @ projw^T + proj_b (no relu)
  mfma_gemm<<<dim3(NN / 128, 1), 256, 0, stream>>>(
      featbf, 384, projwbf, 384, proj_b, 3, 0, (unsigned short*)xbf, 128, 0);

  const size_t seg = (size_t)NN * 128;  // planar Q/K/V segment (elements)
  unsigned short* Qp = (unsigned short*)qkvbf;
  unsigned short* Kp = Qp + seg;
  unsigned short* Vp = Kp + seg;
  for (int layer = 0; layer < 3; ++layer) {
    mfma_gemm<<<dim3(NN / 128, 3), 256, 0, stream>>>(
        xbf, 256, qkvwbf + (size_t)layer * 98304, 256,
        qkv_b + (size_t)layer * 384, 2, 0, Qp, 128, seg);
    attn_kernel<<<NN / 4, 256, 0, stream>>>(
        Qp, Kp, Vp, ctx, lengths, (unsigned short*)obf);
    mfma_gemm<<<dim3(NN / 128, 1), 256, 0, stream>>>(
        obf, 256, outwbf + (size_t)layer * 32768, 256,
        out_b + (size_t)layer * 128, 2, 1, (unsigned short*)xbf, 128, 0);
  }

  edge_fused<<<EE / 128, 256, 0, stream>>>(
      xbf, eu, ev, ef, w1xbf, w1, b1, w2bf, b2, w3, b3, (float*)d_out);
}